// Round 4
// baseline (1250.331 us; speedup 1.0000x reference)
//
#include <hip/hip_runtime.h>

#define TOKENS  8192
#define IN_DIM  4096
#define OUT_DIM 12288
#define GRP     128

#define BM 128
#define BN 128
#define BK 64

typedef __attribute__((ext_vector_type(8))) short  short8;    // 8 bf16 in LDS/regs
typedef __attribute__((ext_vector_type(8))) unsigned short ushort8;
typedef __attribute__((ext_vector_type(4))) float  f32x4;     // MFMA acc

__device__ __forceinline__ unsigned short f2bf(float f) {
    union { float f; unsigned int i; } x; x.f = f;
    unsigned int r = x.i + 0x7FFFu + ((x.i >> 16) & 1u);   // RNE
    return (unsigned short)(r >> 16);
}

__device__ __forceinline__ void gload_lds16(const void* g, void* l) {
    __builtin_amdgcn_global_load_lds(
        (const __attribute__((address_space(1))) void*)g,
        (__attribute__((address_space(3))) void*)l, 16, 0, 0);
}

// ---------------------------------------------------------------------------
// A convert: hidden f32 [TOKENS, IN] -> bf16 [TOKENS, IN]
// ---------------------------------------------------------------------------
__global__ void cvt_kernel(const float* __restrict__ in,
                           unsigned short* __restrict__ out) {
    size_t base = ((size_t)blockIdx.x * blockDim.x + threadIdx.x) * 8;
    float4 a = *reinterpret_cast<const float4*>(in + base);
    float4 b = *reinterpret_cast<const float4*>(in + base + 4);
    ushort8 v;
    v[0] = f2bf(a.x); v[1] = f2bf(a.y); v[2] = f2bf(a.z); v[3] = f2bf(a.w);
    v[4] = f2bf(b.x); v[5] = f2bf(b.y); v[6] = f2bf(b.z); v[7] = f2bf(b.w);
    *reinterpret_cast<ushort8*>(out + base) = v;
}

// ---------------------------------------------------------------------------
// Dequant: packed int4 (byte in int32) [OUT/2, IN] + scales f32 [OUT, IN/128]
//          + pre_quant_scale f32 [IN]  ->  Wd [OUT, IN] bf16 (pqs folded in)
// row 2p = low nibble, row 2p+1 = high nibble, both minus 8.
// ---------------------------------------------------------------------------
__global__ void dequant_kernel(const int* __restrict__ wp,
                               const float* __restrict__ wsc,
                               const float* __restrict__ pqs,
                               unsigned short* __restrict__ Wd) {
    int idx = blockIdx.x * blockDim.x + threadIdx.x;   // (OUT/2)*(IN/4) threads
    int p  = idx >> 10;                 // packed row (IN/4 = 1024 chunks/row)
    int i0 = (idx & 1023) << 2;         // col base (4 cols per thread)
    int g  = i0 >> 7;                   // group (all 4 cols share it)

    const int4 w = *reinterpret_cast<const int4*>(wp + (size_t)p * IN_DIM + i0);
    float slo = wsc[(size_t)(2 * p)     * (IN_DIM / GRP) + g];
    float shi = wsc[(size_t)(2 * p + 1) * (IN_DIM / GRP) + g];
    float4 q = *reinterpret_cast<const float4*>(pqs + i0);

    float qf[4] = { q.x, q.y, q.z, q.w };
    int   wv[4] = { w.x, w.y, w.z, w.w };

    ushort4 lo, hi;
    unsigned short* lop = (unsigned short*)&lo;
    unsigned short* hig = (unsigned short*)&hi;
#pragma unroll
    for (int j = 0; j < 4; ++j) {
        lop[j] = f2bf((float)(( wv[j]       & 0xF) - 8) * slo * qf[j]);
        hig[j] = f2bf((float)(((wv[j] >> 4) & 0xF) - 8) * shi * qf[j]);
    }
    *reinterpret_cast<ushort4*>(Wd + (size_t)(2 * p)     * IN_DIM + i0) = lo;
    *reinterpret_cast<ushort4*>(Wd + (size_t)(2 * p + 1) * IN_DIM + i0) = hi;
}

// ---------------------------------------------------------------------------
// GEMM: C[M,N] = A[M,K] * B[N,K]^T, 128x128 tile, BK=64, 4 waves (2x2),
// 16x16x32 bf16 MFMA, 4x4 acc/wave. C is float32.
// CONV_A: A is f32, converted during staging (reg + ds_write).
//         else A is bf16, staged via global_load_lds width=16 (m97 pattern).
// FUSED_B: B dequantized on the fly from packed weights + f32 scales.
//          else Bd is bf16, staged via global_load_lds width=16.
// ---------------------------------------------------------------------------
template <bool CONV_A, bool FUSED_B>
__global__ __launch_bounds__(256) void gemm_kernel(
    const void* __restrict__ Ap,             // bf16 or f32 [TOKENS, IN]
    const unsigned short* __restrict__ Bd,   // [OUT, IN] bf16 (non-fused path)
    const int* __restrict__ Wp,              // [OUT/2, IN] packed (fused path)
    const float* __restrict__ wsc,           // [OUT, IN/128] f32 (fused path)
    const float* __restrict__ pqs,           // [IN] f32 (fused path)
    float* __restrict__ C) {                 // [TOKENS, OUT] f32

    __shared__ short sA[BM * BK];
    __shared__ short sB[BN * BK];

    const int tid  = threadIdx.x;
    const int lane = tid & 63;
    const int w    = tid >> 6;
    const int wr   = w >> 1, wc = w & 1;    // 2x2 waves, 64x64 each
    const int lr   = lane >> 4;             // k-chunk selector 0..3
    const int lq   = lane & 15;             // row-in-fragment

    // bijective XCD swizzle: 6144 = 8 * 768
    const int nbn = OUT_DIM / BN;           // 96
    int bid = blockIdx.x;
    int swz = (bid & 7) * ((TOKENS / BM) * nbn / 8) + (bid >> 3);
    const int brow = (swz / nbn) * BM;
    const int bcol = (swz % nbn) * BN;

    f32x4 acc[4][4] = {};

    for (int k0 = 0; k0 < IN_DIM; k0 += BK) {
        // ---- stage A ----
#pragma unroll
        for (int c = 0; c < 4; ++c) {
            int off  = c * 4096 + tid * 16;       // dest byte in 16KB tile
            int r    = off >> 7;                  // tile row (128B per row)
            if constexpr (CONV_A) {
                int e = (off & 127) >> 1;         // element col in row
                const float* src = (const float*)Ap + (size_t)(brow + r) * IN_DIM + k0 + e;
                float4 f0 = *reinterpret_cast<const float4*>(src);
                float4 f1 = *reinterpret_cast<const float4*>(src + 4);
                ushort8 v;
                v[0] = f2bf(f0.x); v[1] = f2bf(f0.y); v[2] = f2bf(f0.z); v[3] = f2bf(f0.w);
                v[4] = f2bf(f1.x); v[5] = f2bf(f1.y); v[6] = f2bf(f1.z); v[7] = f2bf(f1.w);
                *reinterpret_cast<ushort8*>((char*)sA + off) = v;
            } else {
                int colb = off & 127;
                gload_lds16((const char*)Ap + ((size_t)(brow + r) * IN_DIM + k0) * 2 + colb,
                            (char*)sA + off);
            }
            if constexpr (!FUSED_B) {
                int colb = off & 127;
                gload_lds16((const char*)Bd + ((size_t)(bcol + r) * IN_DIM + k0) * 2 + colb,
                            (char*)sB + off);
            }
        }
        if constexpr (FUSED_B) {
            // dequant B tile: 64 packed rows x 64 cols int32
#pragma unroll
            for (int c = 0; c < 4; ++c) {
                int pr = c * 16 + (tid >> 4);     // packed row in tile [0,64)
                int i0 = (tid & 15) * 4;          // col in tile [0,64)
                int gp = (bcol >> 1) + pr;
                int gk = k0 + i0;
                int4 wv = *reinterpret_cast<const int4*>(Wp + (size_t)gp * IN_DIM + gk);
                int g = gk >> 7;
                float slo = wsc[(size_t)(2 * gp)     * (IN_DIM / GRP) + g];
                float shi = wsc[(size_t)(2 * gp + 1) * (IN_DIM / GRP) + g];
                float4 q = *reinterpret_cast<const float4*>(pqs + gk);
                float qf[4] = { q.x, q.y, q.z, q.w };
                int wi[4] = { wv.x, wv.y, wv.z, wv.w };
                ushort4 lo, hi;
                unsigned short* lop = (unsigned short*)&lo;
                unsigned short* hig = (unsigned short*)&hi;
#pragma unroll
                for (int j = 0; j < 4; ++j) {
                    lop[j] = f2bf((float)(( wi[j]       & 0xF) - 8) * slo * qf[j]);
                    hig[j] = f2bf((float)(((wi[j] >> 4) & 0xF) - 8) * shi * qf[j]);
                }
                *reinterpret_cast<ushort4*>(&sB[(2 * pr)     * BK + i0]) = lo;
                *reinterpret_cast<ushort4*>(&sB[(2 * pr + 1) * BK + i0]) = hi;
            }
        }
        __syncthreads();   // drains vmcnt(0)+lgkmcnt(0)

        // ---- compute: 2 k-subtiles x 4x4 MFMAs ----
#pragma unroll
        for (int kk = 0; kk < BK; kk += 32) {
            int ko = kk + lr * 8;
            short8 af[4], bf[4];
#pragma unroll
            for (int m = 0; m < 4; ++m)
                af[m] = *reinterpret_cast<const short8*>(&sA[(wr * 64 + m * 16 + lq) * BK + ko]);
#pragma unroll
            for (int n = 0; n < 4; ++n)
                bf[n] = *reinterpret_cast<const short8*>(&sB[(wc * 64 + n * 16 + lq) * BK + ko]);
#pragma unroll
            for (int m = 0; m < 4; ++m)
#pragma unroll
                for (int n = 0; n < 4; ++n)
                    acc[m][n] = __builtin_amdgcn_mfma_f32_16x16x32_bf16(
                        af[m], bf[n], acc[m][n], 0, 0, 0);
        }
        __syncthreads();
    }

    // ---- epilogue: C/D layout col=lane&15, row=(lane>>4)*4+j; C is f32 ----
#pragma unroll
    for (int m = 0; m < 4; ++m)
#pragma unroll
        for (int n = 0; n < 4; ++n)
#pragma unroll
            for (int j = 0; j < 4; ++j) {
                int row = brow + wr * 64 + m * 16 + lr * 4 + j;
                int col = bcol + wc * 64 + n * 16 + lq;
                C[(size_t)row * OUT_DIM + col] = acc[m][n][j];
            }
}

extern "C" void kernel_launch(void* const* d_in, const int* in_sizes, int n_in,
                              void* d_out, int out_size, void* d_ws, size_t ws_size,
                              hipStream_t stream) {
    // --- Resolve inputs BY ELEMENT COUNT (all four are distinct) ---
    // hidden: 33554432 (f32)   weight: 25165824 (int32)
    // wscale: 393216 (f32)     pqs: 4096 (f32)
    const void* p_hidden = nullptr; const void* p_weight = nullptr;
    const void* p_wscale = nullptr; const void* p_pqs = nullptr;
    for (int i = 0; i < n_in; ++i) {
        switch (in_sizes[i]) {
            case 33554432: p_hidden = d_in[i]; break;
            case 25165824: p_weight = d_in[i]; break;
            case 393216:   p_wscale = d_in[i]; break;
            case 4096:     p_pqs    = d_in[i]; break;
            default: break;
        }
    }
    if (!p_hidden || !p_weight || !p_wscale || !p_pqs) {
        p_hidden = d_in[0]; p_weight = d_in[1]; p_wscale = d_in[2]; p_pqs = d_in[3];
    }
    const float* hidden = (const float*)p_hidden;
    const int*   weight = (const int*)p_weight;
    const float* wscale = (const float*)p_wscale;
    const float* pqs    = (const float*)p_pqs;
    float*       out    = (float*)d_out;

    const int nblocks = (TOKENS / BM) * (OUT_DIM / BN);       // 6144
    const size_t wd_bytes = (size_t)OUT_DIM * IN_DIM * 2;     // 96 MB bf16 W
    const size_t ab_bytes = (size_t)TOKENS * IN_DIM * 2;      // 64 MB bf16 A

    if (ws_size >= wd_bytes + ab_bytes) {
        unsigned short* Wd  = (unsigned short*)d_ws;
        unsigned short* Abf = (unsigned short*)((char*)d_ws + wd_bytes);
        dequant_kernel<<<(OUT_DIM / 2) * (IN_DIM / 4) / 256, 256, 0, stream>>>(
            weight, wscale, pqs, Wd);
        cvt_kernel<<<TOKENS * IN_DIM / (256 * 8), 256, 0, stream>>>(hidden, Abf);
        gemm_kernel<false, false><<<nblocks, 256, 0, stream>>>(
            Abf, Wd, nullptr, nullptr, nullptr, out);
    } else if (ws_size >= wd_bytes) {
        unsigned short* Wd = (unsigned short*)d_ws;
        dequant_kernel<<<(OUT_DIM / 2) * (IN_DIM / 4) / 256, 256, 0, stream>>>(
            weight, wscale, pqs, Wd);
        gemm_kernel<true, false><<<nblocks, 256, 0, stream>>>(
            hidden, Wd, nullptr, nullptr, nullptr, out);
    } else {
        gemm_kernel<true, true><<<nblocks, 256, 0, stream>>>(
            hidden, nullptr, weight, wscale, pqs, out);
    }
}

// Round 5
// 845.401 us; speedup vs baseline: 1.4790x; 1.4790x over previous
//
#include <hip/hip_runtime.h>

#define TOKENS  8192
#define IN_DIM  4096
#define OUT_DIM 12288
#define GRP     128

typedef __attribute__((ext_vector_type(8))) short  short8;    // 8 bf16
typedef __attribute__((ext_vector_type(8))) unsigned short ushort8;
typedef __attribute__((ext_vector_type(4))) float  f32x4;     // MFMA acc

__device__ __forceinline__ unsigned short f2bf(float f) {
    union { float f; unsigned int i; } x; x.f = f;
    unsigned int r = x.i + 0x7FFFu + ((x.i >> 16) & 1u);   // RNE
    return (unsigned short)(r >> 16);
}

__device__ __forceinline__ void gload_lds16(const void* g, void* l) {
    __builtin_amdgcn_global_load_lds(
        (const __attribute__((address_space(1))) void*)g,
        (__attribute__((address_space(3))) void*)l, 16, 0, 0);
}

// ---------------------------------------------------------------------------
// A convert: hidden f32 [TOKENS, IN] -> bf16
// ---------------------------------------------------------------------------
__global__ void cvt_kernel(const float* __restrict__ in,
                           unsigned short* __restrict__ out) {
    size_t base = ((size_t)blockIdx.x * blockDim.x + threadIdx.x) * 8;
    float4 a = *reinterpret_cast<const float4*>(in + base);
    float4 b = *reinterpret_cast<const float4*>(in + base + 4);
    ushort8 v;
    v[0] = f2bf(a.x); v[1] = f2bf(a.y); v[2] = f2bf(a.z); v[3] = f2bf(a.w);
    v[4] = f2bf(b.x); v[5] = f2bf(b.y); v[6] = f2bf(b.z); v[7] = f2bf(b.w);
    *reinterpret_cast<ushort8*>(out + base) = v;
}

// ---------------------------------------------------------------------------
// Dequant: packed int4 [OUT/2, IN] + f32 scales [OUT, IN/128] + f32 pqs [IN]
//          -> Wd [OUT, IN] bf16 (pqs folded in)
// ---------------------------------------------------------------------------
__global__ void dequant_kernel(const int* __restrict__ wp,
                               const float* __restrict__ wsc,
                               const float* __restrict__ pqs,
                               unsigned short* __restrict__ Wd) {
    int idx = blockIdx.x * blockDim.x + threadIdx.x;
    int p  = idx >> 10;
    int i0 = (idx & 1023) << 2;
    int g  = i0 >> 7;

    const int4 w = *reinterpret_cast<const int4*>(wp + (size_t)p * IN_DIM + i0);
    float slo = wsc[(size_t)(2 * p)     * (IN_DIM / GRP) + g];
    float shi = wsc[(size_t)(2 * p + 1) * (IN_DIM / GRP) + g];
    float4 q = *reinterpret_cast<const float4*>(pqs + i0);

    float qf[4] = { q.x, q.y, q.z, q.w };
    int   wv[4] = { w.x, w.y, w.z, w.w };

    ushort4 lo, hi;
    unsigned short* lop = (unsigned short*)&lo;
    unsigned short* hig = (unsigned short*)&hi;
#pragma unroll
    for (int j = 0; j < 4; ++j) {
        lop[j] = f2bf((float)(( wv[j]       & 0xF) - 8) * slo * qf[j]);
        hig[j] = f2bf((float)(((wv[j] >> 4) & 0xF) - 8) * shi * qf[j]);
    }
    *reinterpret_cast<ushort4*>(Wd + (size_t)(2 * p)     * IN_DIM + i0) = lo;
    *reinterpret_cast<ushort4*>(Wd + (size_t)(2 * p + 1) * IN_DIM + i0) = hi;
}

// ===========================================================================
// 256x256 8-phase GEMM (T2+T3+T4+T5). C[M,N] = A[M,K] * B[N,K]^T, C f32.
// 512 thr = 8 waves (2M x 4N); per-wave out 128x64; acc[8][4] f32x4.
// LDS: [buf2][A/B][khalf2][16KB]: [256 rows][32 k] bf16, 64B rows,
//   16B-slot XOR swizzle slot^=(row>>1)&3 (linear LDS dest, inverse-swizzled
//   global source, swizzled ds_read).
// Chunk issue (tile t): p0:(t+1)Ak1  p1:(t+1)Bk1  p2:(t+2)Ak0  p3:(t+2)Bk0
// Boundary: vmcnt(4) (tail: 0) + raw barrier once per tile. Never drain mid-loop.
// ===========================================================================
#define BM 256
#define BN 256
#define BK 64
#define NT (IN_DIM / BK)   // 64

__device__ __forceinline__ void stage_chunk(const unsigned short* gbase, int rowbase,
                                            int t, int kh, char* region, int tid) {
#pragma unroll
    for (int c = 0; c < 2; ++c) {
        int off  = c * 8192 + tid * 16;               // linear LDS dest
        int row  = off >> 6;                          // 64B per row
        int slot = (off >> 4) & 3;
        int col  = t * 64 + kh * 32 + ((slot ^ ((row >> 1) & 3)) << 3); // inverse swz
        gload_lds16(gbase + (size_t)(rowbase + row) * IN_DIM + col, region + off);
    }
}

__global__ __launch_bounds__(512, 2) void gemm8p_kernel(
    const unsigned short* __restrict__ A,   // [TOKENS][IN] bf16
    const unsigned short* __restrict__ B,   // [OUT][IN] bf16
    float* __restrict__ C) {                // [TOKENS][OUT] f32

    __shared__ char lds[2][2][2][16384];    // [buf][mat A=0/B=1][khalf][bytes]

    const int tid  = threadIdx.x;
    const int lane = tid & 63;
    const int wid  = tid >> 6;
    const int wm   = wid >> 2;              // 0..1
    const int wn   = wid & 3;               // 0..3
    const int lq   = lane & 15;
    const int lr   = lane >> 4;             // 0..3
    const int sw   = (lr ^ ((lq >> 1) & 3)) << 4;   // swizzled slot byte offset

    // grid 1536 = 8 * 192: bijective XCD swizzle
    int bid = blockIdx.x;
    int swz = (bid & 7) * 192 + (bid >> 3);
    const int brow = (swz / (OUT_DIM / BN)) * BM;
    const int bcol = (swz % (OUT_DIM / BN)) * BN;

    f32x4 acc[8][4] = {};
    short8 afr[4], bfr[4];

    // ---- prologue: tile0 all 4 chunks (buf0) + tile1 k-half0 chunks (buf1) ----
    stage_chunk(A, brow, 0, 0, &lds[0][0][0][0], tid);
    stage_chunk(B, bcol, 0, 0, &lds[0][1][0][0], tid);
    stage_chunk(A, brow, 0, 1, &lds[0][0][1][0], tid);
    stage_chunk(B, bcol, 0, 1, &lds[0][1][1][0], tid);
    stage_chunk(A, brow, 1, 0, &lds[1][0][0][0], tid);
    stage_chunk(B, bcol, 1, 0, &lds[1][1][0][0], tid);
    asm volatile("s_waitcnt vmcnt(4)" ::: "memory");
    __builtin_amdgcn_s_barrier();

    for (int t = 0; t < NT; ++t) {
        const int p = t & 1, q = p ^ 1;

        // ---------- phase 0: k-half 0, m-half 0 ----------
#pragma unroll
        for (int n = 0; n < 4; ++n)
            bfr[n] = *reinterpret_cast<const short8*>(
                &lds[p][1][0][(wn * 64 + n * 16 + lq) * 64 + sw]);
#pragma unroll
        for (int m = 0; m < 4; ++m)
            afr[m] = *reinterpret_cast<const short8*>(
                &lds[p][0][0][(wm * 128 + m * 16 + lq) * 64 + sw]);
        if (t + 1 < NT) stage_chunk(A, brow, t + 1, 1, &lds[q][0][1][0], tid);
        __builtin_amdgcn_s_barrier();
        asm volatile("s_waitcnt lgkmcnt(0)" ::: "memory");
        __builtin_amdgcn_s_setprio(1);
#pragma unroll
        for (int m = 0; m < 4; ++m)
#pragma unroll
            for (int n = 0; n < 4; ++n)
                acc[m][n] = __builtin_amdgcn_mfma_f32_16x16x32_bf16(
                    afr[m], bfr[n], acc[m][n], 0, 0, 0);
        __builtin_amdgcn_s_setprio(0);
        __builtin_amdgcn_s_barrier();

        // ---------- phase 1: k-half 0, m-half 1 (B held in regs) ----------
#pragma unroll
        for (int m = 0; m < 4; ++m)
            afr[m] = *reinterpret_cast<const short8*>(
                &lds[p][0][0][(wm * 128 + (m + 4) * 16 + lq) * 64 + sw]);
        if (t + 1 < NT) stage_chunk(B, bcol, t + 1, 1, &lds[q][1][1][0], tid);
        __builtin_amdgcn_s_barrier();
        asm volatile("s_waitcnt lgkmcnt(0)" ::: "memory");
        __builtin_amdgcn_s_setprio(1);
#pragma unroll
        for (int m = 0; m < 4; ++m)
#pragma unroll
            for (int n = 0; n < 4; ++n)
                acc[m + 4][n] = __builtin_amdgcn_mfma_f32_16x16x32_bf16(
                    afr[m], bfr[n], acc[m + 4][n], 0, 0, 0);
        __builtin_amdgcn_s_setprio(0);
        __builtin_amdgcn_s_barrier();

        // ---------- phase 2: k-half 1, m-half 0 ----------
#pragma unroll
        for (int n = 0; n < 4; ++n)
            bfr[n] = *reinterpret_cast<const short8*>(
                &lds[p][1][1][(wn * 64 + n * 16 + lq) * 64 + sw]);
#pragma unroll
        for (int m = 0; m < 4; ++m)
            afr[m] = *reinterpret_cast<const short8*>(
                &lds[p][0][1][(wm * 128 + m * 16 + lq) * 64 + sw]);
        if (t + 2 < NT) stage_chunk(A, brow, t + 2, 0, &lds[p][0][0][0], tid);
        __builtin_amdgcn_s_barrier();
        asm volatile("s_waitcnt lgkmcnt(0)" ::: "memory");
        __builtin_amdgcn_s_setprio(1);
#pragma unroll
        for (int m = 0; m < 4; ++m)
#pragma unroll
            for (int n = 0; n < 4; ++n)
                acc[m][n] = __builtin_amdgcn_mfma_f32_16x16x32_bf16(
                    afr[m], bfr[n], acc[m][n], 0, 0, 0);
        __builtin_amdgcn_s_setprio(0);
        __builtin_amdgcn_s_barrier();

        // ---------- phase 3: k-half 1, m-half 1 ----------
#pragma unroll
        for (int m = 0; m < 4; ++m)
            afr[m] = *reinterpret_cast<const short8*>(
                &lds[p][0][1][(wm * 128 + (m + 4) * 16 + lq) * 64 + sw]);
        if (t + 2 < NT) stage_chunk(B, bcol, t + 2, 0, &lds[p][1][0][0], tid);
        __builtin_amdgcn_s_barrier();
        asm volatile("s_waitcnt lgkmcnt(0)" ::: "memory");
        __builtin_amdgcn_s_setprio(1);
#pragma unroll
        for (int m = 0; m < 4; ++m)
#pragma unroll
            for (int n = 0; n < 4; ++n)
                acc[m + 4][n] = __builtin_amdgcn_mfma_f32_16x16x32_bf16(
                    afr[m], bfr[n], acc[m + 4][n], 0, 0, 0);
        __builtin_amdgcn_s_setprio(0);
        // ---------- tile boundary: counted vmcnt, never 0 until tail ----------
        if (t + 2 < NT) { asm volatile("s_waitcnt vmcnt(4)" ::: "memory"); }
        else            { asm volatile("s_waitcnt vmcnt(0)" ::: "memory"); }
        __builtin_amdgcn_s_barrier();
    }

    // ---- epilogue: C/D layout col=lane&15, row=(lane>>4)*4+j ----
#pragma unroll
    for (int m = 0; m < 8; ++m)
#pragma unroll
        for (int n = 0; n < 4; ++n)
#pragma unroll
            for (int j = 0; j < 4; ++j) {
                int row = brow + wm * 128 + m * 16 + lr * 4 + j;
                int col = bcol + wn * 64 + n * 16 + lq;
                C[(size_t)row * OUT_DIM + col] = acc[m][n][j];
            }
}

// ---------------------------------------------------------------------------
// Fallback (ws too small): round-4 proven 128x128 2-phase kernel.
// ---------------------------------------------------------------------------
template <bool CONV_A, bool FUSED_B>
__global__ __launch_bounds__(256) void gemm_fb_kernel(
    const void* __restrict__ Ap, const unsigned short* __restrict__ Bd,
    const int* __restrict__ Wp, const float* __restrict__ wsc,
    const float* __restrict__ pqs, float* __restrict__ C) {
    __shared__ short sA[128 * 64];
    __shared__ short sB[128 * 64];
    const int tid  = threadIdx.x;
    const int lane = tid & 63;
    const int w    = tid >> 6;
    const int wr   = w >> 1, wc = w & 1;
    const int lr   = lane >> 4;
    const int lq   = lane & 15;
    const int nbn = OUT_DIM / 128;
    int bid = blockIdx.x;
    int swzb = (bid & 7) * ((TOKENS / 128) * nbn / 8) + (bid >> 3);
    const int brow = (swzb / nbn) * 128;
    const int bcol = (swzb % nbn) * 128;
    f32x4 acc[4][4] = {};
    for (int k0 = 0; k0 < IN_DIM; k0 += 64) {
#pragma unroll
        for (int c = 0; c < 4; ++c) {
            int off  = c * 4096 + tid * 16;
            int r    = off >> 7;
            if constexpr (CONV_A) {
                int e = (off & 127) >> 1;
                const float* src = (const float*)Ap + (size_t)(brow + r) * IN_DIM + k0 + e;
                float4 f0 = *reinterpret_cast<const float4*>(src);
                float4 f1 = *reinterpret_cast<const float4*>(src + 4);
                ushort8 v;
                v[0] = f2bf(f0.x); v[1] = f2bf(f0.y); v[2] = f2bf(f0.z); v[3] = f2bf(f0.w);
                v[4] = f2bf(f1.x); v[5] = f2bf(f1.y); v[6] = f2bf(f1.z); v[7] = f2bf(f1.w);
                *reinterpret_cast<ushort8*>((char*)sA + off) = v;
            } else {
                int colb = off & 127;
                gload_lds16((const char*)Ap + ((size_t)(brow + r) * IN_DIM + k0) * 2 + colb,
                            (char*)sA + off);
            }
            if constexpr (!FUSED_B) {
                int colb = off & 127;
                gload_lds16((const char*)Bd + ((size_t)(bcol + r) * IN_DIM + k0) * 2 + colb,
                            (char*)sB + off);
            }
        }
        if constexpr (FUSED_B) {
#pragma unroll
            for (int c = 0; c < 4; ++c) {
                int pr = c * 16 + (tid >> 4);
                int i0 = (tid & 15) * 4;
                int gp = (bcol >> 1) + pr;
                int gk = k0 + i0;
                int4 wv = *reinterpret_cast<const int4*>(Wp + (size_t)gp * IN_DIM + gk);
                int g = gk >> 7;
                float slo = wsc[(size_t)(2 * gp)     * (IN_DIM / GRP) + g];
                float shi = wsc[(size_t)(2 * gp + 1) * (IN_DIM / GRP) + g];
                float4 qv = *reinterpret_cast<const float4*>(pqs + gk);
                float qf[4] = { qv.x, qv.y, qv.z, qv.w };
                int wi[4] = { wv.x, wv.y, wv.z, wv.w };
                ushort4 lo, hi;
                unsigned short* lop = (unsigned short*)&lo;
                unsigned short* hig = (unsigned short*)&hi;
#pragma unroll
                for (int j = 0; j < 4; ++j) {
                    lop[j] = f2bf((float)(( wi[j]       & 0xF) - 8) * slo * qf[j]);
                    hig[j] = f2bf((float)(((wi[j] >> 4) & 0xF) - 8) * shi * qf[j]);
                }
                *reinterpret_cast<ushort4*>(&sB[(2 * pr)     * 64 + i0]) = lo;
                *reinterpret_cast<ushort4*>(&sB[(2 * pr + 1) * 64 + i0]) = hi;
            }
        }
        __syncthreads();
#pragma unroll
        for (int kk = 0; kk < 64; kk += 32) {
            int ko = kk + lr * 8;
            short8 af[4], bf[4];
#pragma unroll
            for (int m = 0; m < 4; ++m)
                af[m] = *reinterpret_cast<const short8*>(&sA[(wr * 64 + m * 16 + lq) * 64 + ko]);
#pragma unroll
            for (int n = 0; n < 4; ++n)
                bf[n] = *reinterpret_cast<const short8*>(&sB[(wc * 64 + n * 16 + lq) * 64 + ko]);
#pragma unroll
            for (int m = 0; m < 4; ++m)
#pragma unroll
                for (int n = 0; n < 4; ++n)
                    acc[m][n] = __builtin_amdgcn_mfma_f32_16x16x32_bf16(
                        af[m], bf[n], acc[m][n], 0, 0, 0);
        }
        __syncthreads();
    }
#pragma unroll
    for (int m = 0; m < 4; ++m)
#pragma unroll
        for (int n = 0; n < 4; ++n)
#pragma unroll
            for (int j = 0; j < 4; ++j) {
                int row = brow + wr * 64 + m * 16 + lr * 4 + j;
                int col = bcol + wc * 64 + n * 16 + lq;
                C[(size_t)row * OUT_DIM + col] = acc[m][n][j];
            }
}

extern "C" void kernel_launch(void* const* d_in, const int* in_sizes, int n_in,
                              void* d_out, int out_size, void* d_ws, size_t ws_size,
                              hipStream_t stream) {
    // Resolve inputs by element count (all distinct)
    const void* p_hidden = nullptr; const void* p_weight = nullptr;
    const void* p_wscale = nullptr; const void* p_pqs = nullptr;
    for (int i = 0; i < n_in; ++i) {
        switch (in_sizes[i]) {
            case 33554432: p_hidden = d_in[i]; break;
            case 25165824: p_weight = d_in[i]; break;
            case 393216:   p_wscale = d_in[i]; break;
            case 4096:     p_pqs    = d_in[i]; break;
            default: break;
        }
    }
    if (!p_hidden || !p_weight || !p_wscale || !p_pqs) {
        p_hidden = d_in[0]; p_weight = d_in[1]; p_wscale = d_in[2]; p_pqs = d_in[3];
    }
    const float* hidden = (const float*)p_hidden;
    const int*   weight = (const int*)p_weight;
    const float* wscale = (const float*)p_wscale;
    const float* pqs    = (const float*)p_pqs;
    float*       out    = (float*)d_out;

    const size_t wd_bytes = (size_t)OUT_DIM * IN_DIM * 2;     // 96 MB bf16 W
    const size_t ab_bytes = (size_t)TOKENS * IN_DIM * 2;      // 64 MB bf16 A

    if (ws_size >= wd_bytes + ab_bytes) {
        unsigned short* Wd  = (unsigned short*)d_ws;
        unsigned short* Abf = (unsigned short*)((char*)d_ws + wd_bytes);
        dequant_kernel<<<(OUT_DIM / 2) * (IN_DIM / 4) / 256, 256, 0, stream>>>(
            weight, wscale, pqs, Wd);
        cvt_kernel<<<TOKENS * IN_DIM / (256 * 8), 256, 0, stream>>>(hidden, Abf);
        gemm8p_kernel<<<(TOKENS / BM) * (OUT_DIM / BN), 512, 0, stream>>>(Abf, Wd, out);
    } else if (ws_size >= wd_bytes) {
        unsigned short* Wd = (unsigned short*)d_ws;
        dequant_kernel<<<(OUT_DIM / 2) * (IN_DIM / 4) / 256, 256, 0, stream>>>(
            weight, wscale, pqs, Wd);
        gemm_fb_kernel<true, false><<<(TOKENS / 128) * (OUT_DIM / 128), 256, 0, stream>>>(
            hidden, Wd, nullptr, nullptr, nullptr, out);
    } else {
        gemm_fb_kernel<true, true><<<(TOKENS / 128) * (OUT_DIM / 128), 256, 0, stream>>>(
            hidden, nullptr, weight, wscale, pqs, out);
    }
}

// Round 7
// 807.729 us; speedup vs baseline: 1.5480x; 1.0466x over previous
//
#include <hip/hip_runtime.h>

#define TOKENS  8192
#define IN_DIM  4096
#define OUT_DIM 12288
#define GRP     128

typedef __attribute__((ext_vector_type(8))) short  short8;    // 8 bf16
typedef __attribute__((ext_vector_type(8))) unsigned short ushort8;
typedef __attribute__((ext_vector_type(4))) float  f32x4;     // MFMA acc

__device__ __forceinline__ unsigned short f2bf(float f) {
    union { float f; unsigned int i; } x; x.f = f;
    unsigned int r = x.i + 0x7FFFu + ((x.i >> 16) & 1u);   // RNE
    return (unsigned short)(r >> 16);
}

__device__ __forceinline__ void gload_lds16(const void* g, void* l) {
    __builtin_amdgcn_global_load_lds(
        (const __attribute__((address_space(1))) void*)g,
        (__attribute__((address_space(3))) void*)l, 16, 0, 0);
}

// ---------------------------------------------------------------------------
// A convert: hidden f32 [TOKENS, IN] -> bf16
// ---------------------------------------------------------------------------
__global__ void cvt_kernel(const float* __restrict__ in,
                           unsigned short* __restrict__ out) {
    size_t base = ((size_t)blockIdx.x * blockDim.x + threadIdx.x) * 8;
    float4 a = *reinterpret_cast<const float4*>(in + base);
    float4 b = *reinterpret_cast<const float4*>(in + base + 4);
    ushort8 v;
    v[0] = f2bf(a.x); v[1] = f2bf(a.y); v[2] = f2bf(a.z); v[3] = f2bf(a.w);
    v[4] = f2bf(b.x); v[5] = f2bf(b.y); v[6] = f2bf(b.z); v[7] = f2bf(b.w);
    *reinterpret_cast<ushort8*>(out + base) = v;
}

// ---------------------------------------------------------------------------
// Dequant: packed int4 [OUT/2, IN] + f32 scales [OUT, IN/128] + f32 pqs [IN]
//          -> Wd [OUT, IN] bf16 (pqs folded in)
// ---------------------------------------------------------------------------
__global__ void dequant_kernel(const int* __restrict__ wp,
                               const float* __restrict__ wsc,
                               const float* __restrict__ pqs,
                               unsigned short* __restrict__ Wd) {
    int idx = blockIdx.x * blockDim.x + threadIdx.x;
    int p  = idx >> 10;
    int i0 = (idx & 1023) << 2;
    int g  = i0 >> 7;

    const int4 w = *reinterpret_cast<const int4*>(wp + (size_t)p * IN_DIM + i0);
    float slo = wsc[(size_t)(2 * p)     * (IN_DIM / GRP) + g];
    float shi = wsc[(size_t)(2 * p + 1) * (IN_DIM / GRP) + g];
    float4 q = *reinterpret_cast<const float4*>(pqs + i0);

    float qf[4] = { q.x, q.y, q.z, q.w };
    int   wv[4] = { w.x, w.y, w.z, w.w };

    ushort4 lo, hi;
    unsigned short* lop = (unsigned short*)&lo;
    unsigned short* hig = (unsigned short*)&hi;
#pragma unroll
    for (int j = 0; j < 4; ++j) {
        lop[j] = f2bf((float)(( wv[j]       & 0xF) - 8) * slo * qf[j]);
        hig[j] = f2bf((float)(((wv[j] >> 4) & 0xF) - 8) * shi * qf[j]);
    }
    *reinterpret_cast<ushort4*>(Wd + (size_t)(2 * p)     * IN_DIM + i0) = lo;
    *reinterpret_cast<ushort4*>(Wd + (size_t)(2 * p + 1) * IN_DIM + i0) = hi;
}

// ===========================================================================
// 256x256 8-phase GEMM with cross-phase fragment prefetch.
// Sync skeleton = round-5 proven: ONE boundary vmcnt(4)+barrier per tile
// (per-wave vmcnt immediately before a barrier -> cross-wave safe), barriers
// at every phase end. NO manual lgkmcnt: frag ds_reads are normal LDS loads,
// the compiler emits counted lgkmcnt for exactly what each MFMA consumes,
// leaving prefetch reads outstanding -> LDS pipe overlaps MFMA pipe.
// Frag schedule (tile t): phase0 reads frags0(a0,b0)+prefetch a1(k0,mh1);
// phase1 prefetch a0<-k1 mh0, b1<-k1; phase2 prefetch a1<-k1 mh1; phase3 none.
// Stages: p0:A(t+1,k1) p1:B(t+1,k1) p2:A(t+2,k0) p3:B(t+2,k0).
// Overwrite audit: every region's last reader is lgkm-waited >=1 barrier
// before the overwrite stage issues (checked per region).
// ===========================================================================
#define BM 256
#define BN 256
#define BK 64
#define NT (IN_DIM / BK)   // 64

__device__ __forceinline__ void stage_chunk(const unsigned short* gbase, int rowbase,
                                            int t, int kh, char* region, int tid) {
#pragma unroll
    for (int c = 0; c < 2; ++c) {
        int off  = c * 8192 + tid * 16;               // linear LDS dest
        int row  = off >> 6;                          // 64B per row
        int slot = (off >> 4) & 3;
        int col  = t * 64 + kh * 32 + ((slot ^ ((row >> 1) & 3)) << 3); // inverse swz
        gload_lds16(gbase + (size_t)(rowbase + row) * IN_DIM + col, region + off);
    }
}

__global__ __launch_bounds__(512, 2) void gemm8p_kernel(
    const unsigned short* __restrict__ A,   // [TOKENS][IN] bf16
    const unsigned short* __restrict__ B,   // [OUT][IN] bf16
    float* __restrict__ C) {                // [TOKENS][OUT] f32

    __shared__ char lds[2][2][2][16384];    // [buf][mat A=0/B=1][khalf][bytes]

    const int tid  = threadIdx.x;
    const int lane = tid & 63;
    const int wid  = tid >> 6;
    const int wm   = wid >> 2;              // 0..1
    const int wn   = wid & 3;               // 0..3
    const int lq   = lane & 15;
    const int lr   = lane >> 4;             // 0..3
    const int sw   = (lr ^ ((lq >> 1) & 3)) << 4;   // swizzled slot byte offset

    // grid 1536 = 8 * 192: bijective XCD swizzle
    int bid = blockIdx.x;
    int swz = (bid & 7) * 192 + (bid >> 3);
    const int brow = (swz / (OUT_DIM / BN)) * BM;
    const int bcol = (swz % (OUT_DIM / BN)) * BN;

    f32x4 acc[8][4] = {};
    short8 a0[4], a1[4], b0[4], b1[4];

    // ---- prologue: tile0 all 4 chunks (buf0) + tile1 k-half0 (buf1) ----
    stage_chunk(A, brow, 0, 0, &lds[0][0][0][0], tid);
    stage_chunk(B, bcol, 0, 0, &lds[0][1][0][0], tid);
    stage_chunk(A, brow, 0, 1, &lds[0][0][1][0], tid);
    stage_chunk(B, bcol, 0, 1, &lds[0][1][1][0], tid);
    stage_chunk(A, brow, 1, 0, &lds[1][0][0][0], tid);
    stage_chunk(B, bcol, 1, 0, &lds[1][1][0][0], tid);
    asm volatile("s_waitcnt vmcnt(4)" ::: "memory");   // tile0 fully landed
    __builtin_amdgcn_s_barrier();

    for (int t = 0; t < NT; ++t) {
        const int p = t & 1, q = p ^ 1;

        // ---------- phase 0: MFMA(a0=k0 mh0, b0=k0) ----------
#pragma unroll
        for (int n = 0; n < 4; ++n)
            b0[n] = *reinterpret_cast<const short8*>(
                &lds[p][1][0][(wn * 64 + n * 16 + lq) * 64 + sw]);
#pragma unroll
        for (int m = 0; m < 4; ++m)
            a0[m] = *reinterpret_cast<const short8*>(
                &lds[p][0][0][(wm * 128 + m * 16 + lq) * 64 + sw]);
#pragma unroll
        for (int m = 0; m < 4; ++m)   // prefetch phase-1 A frags (k0, mh1)
            a1[m] = *reinterpret_cast<const short8*>(
                &lds[p][0][0][(wm * 128 + (m + 4) * 16 + lq) * 64 + sw]);
        if (t + 1 < NT) stage_chunk(A, brow, t + 1, 1, &lds[q][0][1][0], tid);
        __builtin_amdgcn_s_setprio(1);
#pragma unroll
        for (int m = 0; m < 4; ++m)
#pragma unroll
            for (int n = 0; n < 4; ++n)
                acc[m][n] = __builtin_amdgcn_mfma_f32_16x16x32_bf16(
                    a0[m], b0[n], acc[m][n], 0, 0, 0);
        __builtin_amdgcn_s_setprio(0);
        __builtin_amdgcn_s_barrier();

        // ---------- phase 1: MFMA(a1=k0 mh1, b0) ----------
#pragma unroll
        for (int m = 0; m < 4; ++m)   // prefetch phase-2 A frags (k1, mh0)
            a0[m] = *reinterpret_cast<const short8*>(
                &lds[p][0][1][(wm * 128 + m * 16 + lq) * 64 + sw]);
#pragma unroll
        for (int n = 0; n < 4; ++n)   // prefetch phase-2 B frags (k1)
            b1[n] = *reinterpret_cast<const short8*>(
                &lds[p][1][1][(wn * 64 + n * 16 + lq) * 64 + sw]);
        if (t + 1 < NT) stage_chunk(B, bcol, t + 1, 1, &lds[q][1][1][0], tid);
        __builtin_amdgcn_s_setprio(1);
#pragma unroll
        for (int m = 0; m < 4; ++m)
#pragma unroll
            for (int n = 0; n < 4; ++n)
                acc[m + 4][n] = __builtin_amdgcn_mfma_f32_16x16x32_bf16(
                    a1[m], b0[n], acc[m + 4][n], 0, 0, 0);
        __builtin_amdgcn_s_setprio(0);
        __builtin_amdgcn_s_barrier();

        // ---------- phase 2: MFMA(a0=k1 mh0, b1=k1) ----------
#pragma unroll
        for (int m = 0; m < 4; ++m)   // prefetch phase-3 A frags (k1, mh1)
            a1[m] = *reinterpret_cast<const short8*>(
                &lds[p][0][1][(wm * 128 + (m + 4) * 16 + lq) * 64 + sw]);
        if (t + 2 < NT) stage_chunk(A, brow, t + 2, 0, &lds[p][0][0][0], tid);
        __builtin_amdgcn_s_setprio(1);
#pragma unroll
        for (int m = 0; m < 4; ++m)
#pragma unroll
            for (int n = 0; n < 4; ++n)
                acc[m][n] = __builtin_amdgcn_mfma_f32_16x16x32_bf16(
                    a0[m], b1[n], acc[m][n], 0, 0, 0);
        __builtin_amdgcn_s_setprio(0);
        __builtin_amdgcn_s_barrier();

        // ---------- phase 3: MFMA(a1=k1 mh1, b1) ----------
        if (t + 2 < NT) stage_chunk(B, bcol, t + 2, 0, &lds[p][1][0][0], tid);
        __builtin_amdgcn_s_setprio(1);
#pragma unroll
        for (int m = 0; m < 4; ++m)
#pragma unroll
            for (int n = 0; n < 4; ++n)
                acc[m + 4][n] = __builtin_amdgcn_mfma_f32_16x16x32_bf16(
                    a1[m], b1[n], acc[m + 4][n], 0, 0, 0);
        __builtin_amdgcn_s_setprio(0);
        // ---- boundary: per-wave counted vmcnt BEFORE barrier (cross-wave safe)
        if (t + 2 < NT) { asm volatile("s_waitcnt vmcnt(4)" ::: "memory"); }
        else            { asm volatile("s_waitcnt vmcnt(0)" ::: "memory"); }
        __builtin_amdgcn_s_barrier();
    }

    // ---- epilogue: C/D layout col=lane&15, row=(lane>>4)*4+j ----
#pragma unroll
    for (int m = 0; m < 8; ++m)
#pragma unroll
        for (int n = 0; n < 4; ++n)
#pragma unroll
            for (int j = 0; j < 4; ++j) {
                int row = brow + wm * 128 + m * 16 + lr * 4 + j;
                int col = bcol + wn * 64 + n * 16 + lq;
                __builtin_nontemporal_store(acc[m][n][j], &C[(size_t)row * OUT_DIM + col]);
            }
}

// ---------------------------------------------------------------------------
// Fallback (ws too small): round-4 proven 128x128 2-phase kernel.
// ---------------------------------------------------------------------------
template <bool CONV_A, bool FUSED_B>
__global__ __launch_bounds__(256) void gemm_fb_kernel(
    const void* __restrict__ Ap, const unsigned short* __restrict__ Bd,
    const int* __restrict__ Wp, const float* __restrict__ wsc,
    const float* __restrict__ pqs, float* __restrict__ C) {
    __shared__ short sA[128 * 64];
    __shared__ short sB[128 * 64];
    const int tid  = threadIdx.x;
    const int lane = tid & 63;
    const int w    = tid >> 6;
    const int wr   = w >> 1, wc = w & 1;
    const int lr   = lane >> 4;
    const int lq   = lane & 15;
    const int nbn = OUT_DIM / 128;
    int bid = blockIdx.x;
    int swzb = (bid & 7) * ((TOKENS / 128) * nbn / 8) + (bid >> 3);
    const int brow = (swzb / nbn) * 128;
    const int bcol = (swzb % nbn) * 128;
    f32x4 acc[4][4] = {};
    for (int k0 = 0; k0 < IN_DIM; k0 += 64) {
#pragma unroll
        for (int c = 0; c < 4; ++c) {
            int off  = c * 4096 + tid * 16;
            int r    = off >> 7;
            if constexpr (CONV_A) {
                int e = (off & 127) >> 1;
                const float* src = (const float*)Ap + (size_t)(brow + r) * IN_DIM + k0 + e;
                float4 f0 = *reinterpret_cast<const float4*>(src);
                float4 f1 = *reinterpret_cast<const float4*>(src + 4);
                ushort8 v;
                v[0] = f2bf(f0.x); v[1] = f2bf(f0.y); v[2] = f2bf(f0.z); v[3] = f2bf(f0.w);
                v[4] = f2bf(f1.x); v[5] = f2bf(f1.y); v[6] = f2bf(f1.z); v[7] = f2bf(f1.w);
                *reinterpret_cast<ushort8*>((char*)sA + off) = v;
            } else {
                int colb = off & 127;
                gload_lds16((const char*)Ap + ((size_t)(brow + r) * IN_DIM + k0) * 2 + colb,
                            (char*)sA + off);
            }
            if constexpr (!FUSED_B) {
                int colb = off & 127;
                gload_lds16((const char*)Bd + ((size_t)(bcol + r) * IN_DIM + k0) * 2 + colb,
                            (char*)sB + off);
            }
        }
        if constexpr (FUSED_B) {
#pragma unroll
            for (int c = 0; c < 4; ++c) {
                int pr = c * 16 + (tid >> 4);
                int i0 = (tid & 15) * 4;
                int gp = (bcol >> 1) + pr;
                int gk = k0 + i0;
                int4 wv = *reinterpret_cast<const int4*>(Wp + (size_t)gp * IN_DIM + gk);
                int g = gk >> 7;
                float slo = wsc[(size_t)(2 * gp)     * (IN_DIM / GRP) + g];
                float shi = wsc[(size_t)(2 * gp + 1) * (IN_DIM / GRP) + g];
                float4 qv = *reinterpret_cast<const float4*>(pqs + gk);
                float qf[4] = { qv.x, qv.y, qv.z, qv.w };
                int wi[4] = { wv.x, wv.y, wv.z, wv.w };
                ushort4 lo, hi;
                unsigned short* lop = (unsigned short*)&lo;
                unsigned short* hig = (unsigned short*)&hi;
#pragma unroll
                for (int j = 0; j < 4; ++j) {
                    lop[j] = f2bf((float)(( wi[j]       & 0xF) - 8) * slo * qf[j]);
                    hig[j] = f2bf((float)(((wi[j] >> 4) & 0xF) - 8) * shi * qf[j]);
                }
                *reinterpret_cast<ushort4*>(&sB[(2 * pr)     * 64 + i0]) = lo;
                *reinterpret_cast<ushort4*>(&sB[(2 * pr + 1) * 64 + i0]) = hi;
            }
        }
        __syncthreads();
#pragma unroll
        for (int kk = 0; kk < 64; kk += 32) {
            int ko = kk + lr * 8;
            short8 af[4], bf[4];
#pragma unroll
            for (int m = 0; m < 4; ++m)
                af[m] = *reinterpret_cast<const short8*>(&sA[(wr * 64 + m * 16 + lq) * 64 + ko]);
#pragma unroll
            for (int n = 0; n < 4; ++n)
                bf[n] = *reinterpret_cast<const short8*>(&sB[(wc * 64 + n * 16 + lq) * 64 + ko]);
#pragma unroll
            for (int m = 0; m < 4; ++m)
#pragma unroll
                for (int n = 0; n < 4; ++n)
                    acc[m][n] = __builtin_amdgcn_mfma_f32_16x16x32_bf16(
                        af[m], bf[n], acc[m][n], 0, 0, 0);
        }
        __syncthreads();
    }
#pragma unroll
    for (int m = 0; m < 4; ++m)
#pragma unroll
        for (int n = 0; n < 4; ++n)
#pragma unroll
            for (int j = 0; j < 4; ++j) {
                int row = brow + wr * 64 + m * 16 + lr * 4 + j;
                int col = bcol + wc * 64 + n * 16 + lq;
                C[(size_t)row * OUT_DIM + col] = acc[m][n][j];
            }
}

extern "C" void kernel_launch(void* const* d_in, const int* in_sizes, int n_in,
                              void* d_out, int out_size, void* d_ws, size_t ws_size,
                              hipStream_t stream) {
    // Resolve inputs by element count (all distinct)
    const void* p_hidden = nullptr; const void* p_weight = nullptr;
    const void* p_wscale = nullptr; const void* p_pqs = nullptr;
    for (int i = 0; i < n_in; ++i) {
        switch (in_sizes[i]) {
            case 33554432: p_hidden = d_in[i]; break;
            case 25165824: p_weight = d_in[i]; break;
            case 393216:   p_wscale = d_in[i]; break;
            case 4096:     p_pqs    = d_in[i]; break;
            default: break;
        }
    }
    if (!p_hidden || !p_weight || !p_wscale || !p_pqs) {
        p_hidden = d_in[0]; p_weight = d_in[1]; p_wscale = d_in[2]; p_pqs = d_in[3];
    }
    const float* hidden = (const float*)p_hidden;
    const int*   weight = (const int*)p_weight;
    const float* wscale = (const float*)p_wscale;
    const float* pqs    = (const float*)p_pqs;
    float*       out    = (float*)d_out;

    const size_t wd_bytes = (size_t)OUT_DIM * IN_DIM * 2;     // 96 MB bf16 W
    const size_t ab_bytes = (size_t)TOKENS * IN_DIM * 2;      // 64 MB bf16 A

    if (ws_size >= wd_bytes + ab_bytes) {
        unsigned short* Wd  = (unsigned short*)d_ws;
        unsigned short* Abf = (unsigned short*)((char*)d_ws + wd_bytes);
        dequant_kernel<<<(OUT_DIM / 2) * (IN_DIM / 4) / 256, 256, 0, stream>>>(
            weight, wscale, pqs, Wd);
        cvt_kernel<<<TOKENS * IN_DIM / (256 * 8), 256, 0, stream>>>(hidden, Abf);
        gemm8p_kernel<<<(TOKENS / BM) * (OUT_DIM / BN), 512, 0, stream>>>(Abf, Wd, out);
    } else if (ws_size >= wd_bytes) {
        unsigned short* Wd = (unsigned short*)d_ws;
        dequant_kernel<<<(OUT_DIM / 2) * (IN_DIM / 4) / 256, 256, 0, stream>>>(
            weight, wscale, pqs, Wd);
        gemm_fb_kernel<true, false><<<(TOKENS / 128) * (OUT_DIM / 128), 256, 0, stream>>>(
            hidden, Wd, nullptr, nullptr, nullptr, out);
    } else {
        gemm_fb_kernel<true, true><<<(TOKENS / 128) * (OUT_DIM / 128), 256, 0, stream>>>(
            hidden, nullptr, weight, wscale, pqs, out);
    }
}